// Round 4
// baseline (123.867 us; speedup 1.0000x reference)
//
#include <hip/hip_runtime.h>
#include <math.h>

#define NG 1024      // gaussians per view
#define HH 128
#define WW 128
#define NV 2         // views
#define SH_C0 0.28209479177387814f
#define SH_C1 0.4886025119029199f

#define RECF 12                     // floats per gaussian record (3x float4)
#define REC_UN   0                  // unsorted records (float offset)
#define REC_SORT (NV*NG*RECF)       // sorted records  (float offset)
#define KEY_OFF  (2*NV*NG*RECF)     // depth keys as uint64[] (float offset; 8B aligned)

#define PIX 16                      // pixels per render block
#define CH  16                      // depth chunks per pixel
#define GPC (NG/CH)                 // gaussians per chunk = 64

// ---------------- Kernel 1: per-gaussian preprocess (no sort) ----------------
// grid = NV*8 blocks x 128 threads (spread across 16 CUs).
// record: [u,v,A,B | C,pwmin,op,r | g,b,0,0]  with A=-0.5ca, B=-cb, C=-0.5cc
__global__ __launch_bounds__(128) void preprocess_kernel(
    const float* __restrict__ xyz, const float* __restrict__ feats,
    const float* __restrict__ scaling, const float* __restrict__ rotation,
    const float* __restrict__ opacity, const float* __restrict__ C2W,
    const float* __restrict__ intr, float* __restrict__ ws)
{
    const int iv = blockIdx.x >> 3;
    const int i  = ((blockIdx.x & 7) << 7) + threadIdx.x;

    const float* c2w = C2W + iv * 16;   // row-major 4x4
    const float fx = intr[iv*4+0], fy = intr[iv*4+1];
    const float cx = intr[iv*4+2], cy = intr[iv*4+3];

    // rigid inverse: Rcw = R^T, tcw = -R^T t
    float Rcw[3][3], tcw[3];
    #pragma unroll
    for (int r = 0; r < 3; ++r)
        #pragma unroll
        for (int c = 0; c < 3; ++c)
            Rcw[r][c] = c2w[c*4 + r];
    #pragma unroll
    for (int r = 0; r < 3; ++r)
        tcw[r] = -(Rcw[r][0]*c2w[3] + Rcw[r][1]*c2w[7] + Rcw[r][2]*c2w[11]);
    const float camx = c2w[3], camy = c2w[7], camz = c2w[11];

    const float X = xyz[i*3+0], Y = xyz[i*3+1], Z = xyz[i*3+2];

    // quaternion -> rotation
    float qw = rotation[i*4+0], qx = rotation[i*4+1];
    float qy = rotation[i*4+2], qz = rotation[i*4+3];
    const float qn = rsqrtf(qw*qw + qx*qx + qy*qy + qz*qz);
    qw *= qn; qx *= qn; qy *= qn; qz *= qn;
    const float R00 = 1.f - 2.f*(qy*qy + qz*qz);
    const float R01 = 2.f*(qx*qy - qw*qz);
    const float R02 = 2.f*(qx*qz + qw*qy);
    const float R10 = 2.f*(qx*qy + qw*qz);
    const float R11 = 1.f - 2.f*(qx*qx + qz*qz);
    const float R12 = 2.f*(qy*qz - qw*qx);
    const float R20 = 2.f*(qx*qz - qw*qy);
    const float R21 = 2.f*(qy*qz + qw*qx);
    const float R22 = 1.f - 2.f*(qx*qx + qy*qy);

    const float s0 = scaling[i*3+0], s1 = scaling[i*3+1], s2 = scaling[i*3+2];
    const float M00 = R00*s0, M01 = R01*s1, M02 = R02*s2;
    const float M10 = R10*s0, M11 = R11*s1, M12 = R12*s2;
    const float M20 = R20*s0, M21 = R21*s1, M22 = R22*s2;

    // cov3d = M M^T (symmetric)
    const float S00 = M00*M00 + M01*M01 + M02*M02;
    const float S01 = M00*M10 + M01*M11 + M02*M12;
    const float S02 = M00*M20 + M01*M21 + M02*M22;
    const float S11 = M10*M10 + M11*M11 + M12*M12;
    const float S12 = M10*M20 + M11*M21 + M12*M22;
    const float S22 = M20*M20 + M21*M21 + M22*M22;

    // cov_cam = Rcw * S * Rcw^T
    float tmp[3][3];
    const float S[3][3] = {{S00,S01,S02},{S01,S11,S12},{S02,S12,S22}};
    #pragma unroll
    for (int r = 0; r < 3; ++r)
        #pragma unroll
        for (int c = 0; c < 3; ++c)
            tmp[r][c] = Rcw[r][0]*S[0][c] + Rcw[r][1]*S[1][c] + Rcw[r][2]*S[2][c];
    float C[3][3];
    #pragma unroll
    for (int r = 0; r < 3; ++r)
        #pragma unroll
        for (int c = 0; c < 3; ++c)
            C[r][c] = tmp[r][0]*Rcw[c][0] + tmp[r][1]*Rcw[c][1] + tmp[r][2]*Rcw[c][2];

    // camera-space position
    const float px_ = Rcw[0][0]*X + Rcw[0][1]*Y + Rcw[0][2]*Z + tcw[0];
    const float py_ = Rcw[1][0]*X + Rcw[1][1]*Y + Rcw[1][2]*Z + tcw[1];
    const float pz_ = Rcw[2][0]*X + Rcw[2][1]*Y + Rcw[2][2]*Z + tcw[2];

    const bool valid = pz_ > 0.2f;
    const float zs = fmaxf(pz_, 0.2f);
    const float izs = 1.f / zs;

    const float u = fx*px_*izs + cx;
    const float v = fy*py_*izs + cy;

    // J rows: (a00, 0, a02), (0, a11, a12)
    const float a00 = fx*izs;
    const float a02 = -fx*px_*izs*izs;
    const float a11 = fy*izs;
    const float a12 = -fy*py_*izs*izs;

    const float c00 = a00*a00*C[0][0] + 2.f*a00*a02*C[0][2] + a02*a02*C[2][2] + 0.3f;
    const float c01 = a00*a11*C[0][1] + a00*a12*C[0][2] + a02*a11*C[1][2] + a02*a12*C[2][2];
    const float c11 = a11*a11*C[1][1] + 2.f*a11*a12*C[1][2] + a12*a12*C[2][2] + 0.3f;

    const float det = fmaxf(c00*c11 - c01*c01, 1e-6f);
    const float idet = 1.f / det;

    // SH color (degree 1)
    float dx = X - camx, dy = Y - camy, dz = Z - camz;
    const float dn = rsqrtf(dx*dx + dy*dy + dz*dz);
    dx *= dn; dy *= dn; dz *= dn;
    const float* f = feats + i*12;   // [4][3]
    float col[3];
    #pragma unroll
    for (int c = 0; c < 3; ++c) {
        float cc_ = SH_C0*f[0*3+c] - SH_C1*dy*f[1*3+c] + SH_C1*dz*f[2*3+c]
                    - SH_C1*dx*f[3*3+c] + 0.5f;
        col[c] = fmaxf(cc_, 0.f);
    }

    const float op = valid ? opacity[i] : 0.f;
    const float pwmin = -logf(255.f * op);   // op=0 -> +inf -> gaussian always skipped

    // conic pre-negated/halved: pw = A*du^2 + C*dv^2 + B*du*dv
    const float Aq = -0.5f * (c11*idet);
    const float Bq = c01*idet;             // = -(-c01/det)
    const float Cq = -0.5f * (c00*idet);

    float* rec = ws + REC_UN + (size_t)(iv*NG + i)*RECF;
    rec[0]  = u;     rec[1]  = v;      rec[2]  = Aq;     rec[3]  = Bq;
    rec[4]  = Cq;    rec[5]  = pwmin;  rec[6]  = op;     rec[7]  = col[0];
    rec[8]  = col[1];rec[9]  = col[2]; rec[10] = 0.f;    rec[11] = 0.f;

    // Exact lexicographic (z, index) key via IEEE bit-pattern monotonicity.
    // All z candidates positive => uint32 pattern strictly monotone in z.
    unsigned long long* keys = (unsigned long long*)(ws + KEY_OFF);
    const float zk = valid ? pz_ : 100000.0f;
    keys[iv*NG + i] = (((unsigned long long)__float_as_uint(zk)) << 10)
                    | (unsigned long long)(unsigned)i;
}

// ---------------- Kernel 2: rank computation + sorted scatter ----------------
// grid = NV*8 blocks, block = 256 threads (2 threads per gaussian, 512 keys each)
__global__ __launch_bounds__(256) void rank_scatter_kernel(float* __restrict__ ws)
{
    __shared__ int s_cnt[256];
    const int iv  = blockIdx.x >> 3;
    const int seg = blockIdx.x & 7;
    const int t   = threadIdx.x;
    const int g    = seg*128 + (t & 127);
    const int half = t >> 7;

    const unsigned long long* keys =
        ((const unsigned long long*)(ws + KEY_OFF)) + iv*NG;
    const unsigned long long ki = keys[g];
    const unsigned long long* kp = keys + half*512;
    int cnt = 0;
    #pragma unroll 8
    for (int j = 0; j < 512; ++j)
        cnt += (kp[j] < ki) ? 1 : 0;
    s_cnt[t] = cnt;
    __syncthreads();

    if (t < 128) {
        const int gg   = seg*128 + t;
        const int rank = s_cnt[t] + s_cnt[t+128];
        const float4* src = (const float4*)(ws + REC_UN   + (size_t)(iv*NG + gg)*RECF);
        float4*       dst = (float4*)      (ws + REC_SORT + (size_t)(iv*NG + rank)*RECF);
        dst[0] = src[0]; dst[1] = src[1]; dst[2] = src[2];
    }
}

// ---------------- Kernel 3: chunk-parallel front-to-back compositing ----------------
// block = 256 threads = PIX pixels x CH chunks; grid = NV * (HH*WW/PIX)
__global__ __launch_bounds__(256) void render_kernel(
    const float* __restrict__ ws, float* __restrict__ out)
{
    __shared__ float s_r[CH][PIX], s_g[CH][PIX], s_b[CH][PIX], s_T[CH][PIX];

    const int bpv   = (HH*WW) / PIX;            // 1024 blocks per view
    const int iv    = blockIdx.x / bpv;
    const int pbase = (blockIdx.x % bpv) * PIX;
    const int pl    = threadIdx.x & (PIX-1);
    const int ch    = threadIdx.x >> 4;
    const int pix   = pbase + pl;
    const float gx  = (pix % WW) + 0.5f;
    const float gy  = (pix / WW) + 0.5f;

    // this thread's depth chunk of sorted records
    const float4* gp = (const float4*)(ws + REC_SORT + (size_t)(iv*NG + ch*GPC)*RECF);

    float T = 1.f, ar = 0.f, ag = 0.f, ab = 0.f;

    #pragma unroll 4
    for (int j = 0; j < GPC; ++j) {
        const float4 g0 = gp[j*3+0];            // u,v,A,B
        const float4 g1 = gp[j*3+1];            // C,pwmin,op,r
        const float du = gx - g0.x;
        const float dv = gy - g0.y;
        // pw = A*du^2 + C*dv^2 + B*du*dv (pure fma chain)
        const float pw = fmaf(g0.z, du*du, fmaf(g1.x, dv*dv, g0.w*(du*dv)));
        if (pw <= 0.f && pw >= g1.y) {          // passes alpha >= 1/255 pre-test
            float al = fminf(0.99f, g1.z * __expf(pw));
            if (al >= (1.f/255.f)) {
                const float4 g2 = gp[j*3+2];    // g,b,-,-
                const float w = al * T;
                ar += w * g1.w;
                ag += w * g2.x;
                ab += w * g2.y;
                T *= (1.f - al);
                if (T < 1e-5f) break;           // local chunk transmittance saturated
            }
        }
    }

    s_r[ch][pl] = ar; s_g[ch][pl] = ag; s_b[ch][pl] = ab; s_T[ch][pl] = T;
    __syncthreads();

    // serial prefix-combine over the 16 chunks (associative compositing)
    if (threadIdx.x < PIX) {
        const int p = threadIdx.x;
        float Tg = 1.f, r = 0.f, g = 0.f, b = 0.f;
        #pragma unroll
        for (int c = 0; c < CH; ++c) {
            r += Tg * s_r[c][p];
            g += Tg * s_g[c][p];
            b += Tg * s_b[c][p];
            Tg *= s_T[c][p];
        }
        const int pix2 = pbase + p;
        const int py2 = pix2 / WW, px2 = pix2 % WW;
        out[((iv*3 + 0)*HH + py2)*WW + px2] = r;
        out[((iv*3 + 1)*HH + py2)*WW + px2] = g;
        out[((iv*3 + 2)*HH + py2)*WW + px2] = b;
    }
}

extern "C" void kernel_launch(void* const* d_in, const int* in_sizes, int n_in,
                              void* d_out, int out_size, void* d_ws, size_t ws_size,
                              hipStream_t stream) {
    const float* xyz      = (const float*)d_in[0];
    const float* feats    = (const float*)d_in[1];
    const float* scaling  = (const float*)d_in[2];
    const float* rotation = (const float*)d_in[3];
    const float* opacity  = (const float*)d_in[4];
    // d_in[5] = height, d_in[6] = width (fixed 128x128)
    const float* C2W      = (const float*)d_in[7];
    const float* intr     = (const float*)d_in[8];

    float* ws  = (float*)d_ws;    // needs (2*NV*NG*12)*4 + NV*NG*8 = ~208 KiB
    float* out = (float*)d_out;

    preprocess_kernel<<<NV*8, 128, 0, stream>>>(
        xyz, feats, scaling, rotation, opacity, C2W, intr, ws);

    rank_scatter_kernel<<<NV*8, 256, 0, stream>>>(ws);

    render_kernel<<<NV * (HH*WW / PIX), 256, 0, stream>>>(ws, out);
}

// Round 5
// 112.582 us; speedup vs baseline: 1.1002x; 1.1002x over previous
//
#include <hip/hip_runtime.h>
#include <math.h>

#define NG 1024      // gaussians per view
#define HH 128
#define WW 128
#define NV 2         // views
#define SH_C0 0.28209479177387814f
#define SH_C1 0.4886025119029199f

#define RECF 12                     // floats per gaussian record (3x float4)
#define REC_SORT 0                  // sorted records (float offset in ws)

#define PIX 16                      // pixels per render block
#define CH  16                      // depth chunks per pixel
#define GPC (NG/CH)                 // gaussians per chunk = 64

// ---------------- Kernel A: fused preprocess + rank + sorted scatter ----------------
// grid = NV*8 blocks x 256 threads. Each block:
//   phase a: computes ALL 1024 depth keys of its view into LDS (cheap: one dot product)
//   phase b: rank-by-count for its 128 gaussians (2 threads/gaussian, broadcast LDS reads)
//   phase c: full preprocess for its 128 gaussians, scatter record to sorted slot
// record: [u,v,A,B | C,pwmin,op,r | g,b,0,0]  with A=-0.5ca, B=-cb, C=-0.5cc
__global__ __launch_bounds__(256) void prep_rank_kernel(
    const float* __restrict__ xyz, const float* __restrict__ feats,
    const float* __restrict__ scaling, const float* __restrict__ rotation,
    const float* __restrict__ opacity, const float* __restrict__ C2W,
    const float* __restrict__ intr, float* __restrict__ ws)
{
    __shared__ unsigned long long s_key[NG];   // 8 KiB
    __shared__ int s_cnt[256];

    const int iv  = blockIdx.x >> 3;
    const int seg = blockIdx.x & 7;
    const int t   = threadIdx.x;

    const float* c2w = C2W + iv * 16;   // row-major 4x4
    // Rcw = R^T; row 2 of Rcw = column 2 of R: Rcw[2][c] = c2w[c*4+2]
    const float r20 = c2w[2], r21 = c2w[6], r22 = c2w[10];
    const float tc2 = -(r20*c2w[3] + r21*c2w[7] + r22*c2w[11]);

    // ---- phase a: all 1024 keys of this view (4 per thread) ----
    #pragma unroll
    for (int k = 0; k < 4; ++k) {
        const int g = k*256 + t;
        const float X = xyz[g*3+0], Y = xyz[g*3+1], Z = xyz[g*3+2];
        const float pz = r20*X + r21*Y + r22*Z + tc2;
        // valid => pz > 0.2 > 0, invalid => 1e5: IEEE bits strictly monotone in z.
        const float zk = (pz > 0.2f) ? pz : 100000.0f;
        s_key[g] = (((unsigned long long)__float_as_uint(zk)) << 10)
                 | (unsigned long long)(unsigned)g;
    }
    __syncthreads();

    // ---- phase b: rank count (2 threads per gaussian, 512 keys each) ----
    const int g    = seg*128 + (t & 127);
    const int half = t >> 7;
    const unsigned long long ki = s_key[g];
    {
        const unsigned long long* kp = s_key + half*512;
        int cnt = 0;
        #pragma unroll 8
        for (int j = 0; j < 512; ++j)
            cnt += (kp[j] < ki) ? 1 : 0;
        s_cnt[t] = cnt;
    }
    __syncthreads();

    if (t >= 128) return;
    const int rank = s_cnt[t] + s_cnt[t+128];

    // ---- phase c: full preprocess for gaussian g, write to sorted slot ----
    const float fx = intr[iv*4+0], fy = intr[iv*4+1];
    const float cx = intr[iv*4+2], cy = intr[iv*4+3];

    float Rcw[3][3], tcw[3];
    #pragma unroll
    for (int r = 0; r < 3; ++r)
        #pragma unroll
        for (int c = 0; c < 3; ++c)
            Rcw[r][c] = c2w[c*4 + r];
    #pragma unroll
    for (int r = 0; r < 3; ++r)
        tcw[r] = -(Rcw[r][0]*c2w[3] + Rcw[r][1]*c2w[7] + Rcw[r][2]*c2w[11]);
    const float camx = c2w[3], camy = c2w[7], camz = c2w[11];

    const float X = xyz[g*3+0], Y = xyz[g*3+1], Z = xyz[g*3+2];

    // quaternion -> rotation
    float qw = rotation[g*4+0], qx = rotation[g*4+1];
    float qy = rotation[g*4+2], qz = rotation[g*4+3];
    const float qn = rsqrtf(qw*qw + qx*qx + qy*qy + qz*qz);
    qw *= qn; qx *= qn; qy *= qn; qz *= qn;
    const float R00 = 1.f - 2.f*(qy*qy + qz*qz);
    const float R01 = 2.f*(qx*qy - qw*qz);
    const float R02 = 2.f*(qx*qz + qw*qy);
    const float R10 = 2.f*(qx*qy + qw*qz);
    const float R11 = 1.f - 2.f*(qx*qx + qz*qz);
    const float R12 = 2.f*(qy*qz - qw*qx);
    const float R20 = 2.f*(qx*qz - qw*qy);
    const float R21 = 2.f*(qy*qz + qw*qx);
    const float R22 = 1.f - 2.f*(qx*qx + qy*qy);

    const float s0 = scaling[g*3+0], s1 = scaling[g*3+1], s2 = scaling[g*3+2];
    const float M00 = R00*s0, M01 = R01*s1, M02 = R02*s2;
    const float M10 = R10*s0, M11 = R11*s1, M12 = R12*s2;
    const float M20 = R20*s0, M21 = R21*s1, M22 = R22*s2;

    // cov3d = M M^T (symmetric)
    const float S00 = M00*M00 + M01*M01 + M02*M02;
    const float S01 = M00*M10 + M01*M11 + M02*M12;
    const float S02 = M00*M20 + M01*M21 + M02*M22;
    const float S11 = M10*M10 + M11*M11 + M12*M12;
    const float S12 = M10*M20 + M11*M21 + M12*M22;
    const float S22 = M20*M20 + M21*M21 + M22*M22;

    // cov_cam = Rcw * S * Rcw^T
    float tmp[3][3];
    const float S[3][3] = {{S00,S01,S02},{S01,S11,S12},{S02,S12,S22}};
    #pragma unroll
    for (int r = 0; r < 3; ++r)
        #pragma unroll
        for (int c = 0; c < 3; ++c)
            tmp[r][c] = Rcw[r][0]*S[0][c] + Rcw[r][1]*S[1][c] + Rcw[r][2]*S[2][c];
    float C[3][3];
    #pragma unroll
    for (int r = 0; r < 3; ++r)
        #pragma unroll
        for (int c = 0; c < 3; ++c)
            C[r][c] = tmp[r][0]*Rcw[c][0] + tmp[r][1]*Rcw[c][1] + tmp[r][2]*Rcw[c][2];

    // camera-space x,y; z recovered from the key so ordering & projection agree
    const float px_ = Rcw[0][0]*X + Rcw[0][1]*Y + Rcw[0][2]*Z + tcw[0];
    const float py_ = Rcw[1][0]*X + Rcw[1][1]*Y + Rcw[1][2]*Z + tcw[1];
    const float zf  = __uint_as_float((unsigned)(ki >> 10));
    const bool valid = zf < 99999.0f;            // invalid marker is 1e5

    const float zs = fmaxf(zf, 0.2f);
    const float izs = 1.f / zs;

    const float u = fx*px_*izs + cx;
    const float v = fy*py_*izs + cy;

    // J rows: (a00, 0, a02), (0, a11, a12)
    const float a00 = fx*izs;
    const float a02 = -fx*px_*izs*izs;
    const float a11 = fy*izs;
    const float a12 = -fy*py_*izs*izs;

    const float c00 = a00*a00*C[0][0] + 2.f*a00*a02*C[0][2] + a02*a02*C[2][2] + 0.3f;
    const float c01 = a00*a11*C[0][1] + a00*a12*C[0][2] + a02*a11*C[1][2] + a02*a12*C[2][2];
    const float c11 = a11*a11*C[1][1] + 2.f*a11*a12*C[1][2] + a12*a12*C[2][2] + 0.3f;

    const float det = fmaxf(c00*c11 - c01*c01, 1e-6f);
    const float idet = 1.f / det;

    // SH color (degree 1)
    float dx = X - camx, dy = Y - camy, dz = Z - camz;
    const float dn = rsqrtf(dx*dx + dy*dy + dz*dz);
    dx *= dn; dy *= dn; dz *= dn;
    const float* f = feats + g*12;   // [4][3]
    float col[3];
    #pragma unroll
    for (int c = 0; c < 3; ++c) {
        float cc_ = SH_C0*f[0*3+c] - SH_C1*dy*f[1*3+c] + SH_C1*dz*f[2*3+c]
                    - SH_C1*dx*f[3*3+c] + 0.5f;
        col[c] = fmaxf(cc_, 0.f);
    }

    const float op = valid ? opacity[g] : 0.f;
    const float pwmin = -logf(255.f * op);   // op=0 -> +inf -> always skipped

    // conic pre-negated/halved: pw = A*du^2 + C*dv^2 + B*du*dv
    const float Aq = -0.5f * (c11*idet);
    const float Bq = c01*idet;
    const float Cq = -0.5f * (c00*idet);

    float4* dst = (float4*)(ws + REC_SORT + (size_t)(iv*NG + rank)*RECF);
    dst[0] = make_float4(u,  v,  Aq,    Bq);
    dst[1] = make_float4(Cq, pwmin, op, col[0]);
    dst[2] = make_float4(col[1], col[2], 0.f, 0.f);
}

// ---------------- Kernel B: chunk-parallel front-to-back compositing ----------------
// block = 256 threads = PIX pixels x CH chunks; grid = NV * (HH*WW/PIX)
__global__ __launch_bounds__(256) void render_kernel(
    const float* __restrict__ ws, float* __restrict__ out)
{
    __shared__ float s_r[CH][PIX], s_g[CH][PIX], s_b[CH][PIX], s_T[CH][PIX];

    const int bpv   = (HH*WW) / PIX;            // 1024 blocks per view
    const int iv    = blockIdx.x / bpv;
    const int pbase = (blockIdx.x % bpv) * PIX;
    const int pl    = threadIdx.x & (PIX-1);
    const int ch    = threadIdx.x >> 4;
    const int pix   = pbase + pl;
    const float gx  = (pix % WW) + 0.5f;
    const float gy  = (pix / WW) + 0.5f;

    // this thread's depth chunk of sorted records
    const float4* gp = (const float4*)(ws + REC_SORT + (size_t)(iv*NG + ch*GPC)*RECF);

    float T = 1.f, ar = 0.f, ag = 0.f, ab = 0.f;

    #pragma unroll 4
    for (int j = 0; j < GPC; ++j) {
        const float4 g0 = gp[j*3+0];            // u,v,A,B
        const float4 g1 = gp[j*3+1];            // C,pwmin,op,r
        const float du = gx - g0.x;
        const float dv = gy - g0.y;
        // pw = A*du^2 + C*dv^2 + B*du*dv (pure fma chain)
        const float pw = fmaf(g0.z, du*du, fmaf(g1.x, dv*dv, g0.w*(du*dv)));
        if (pw <= 0.f && pw >= g1.y) {          // passes alpha >= 1/255 pre-test
            float al = fminf(0.99f, g1.z * __expf(pw));
            if (al >= (1.f/255.f)) {
                const float4 g2 = gp[j*3+2];    // g,b,-,-
                const float w = al * T;
                ar += w * g1.w;
                ag += w * g2.x;
                ab += w * g2.y;
                T *= (1.f - al);
                if (T < 1e-5f) break;           // local chunk transmittance saturated
            }
        }
    }

    s_r[ch][pl] = ar; s_g[ch][pl] = ag; s_b[ch][pl] = ab; s_T[ch][pl] = T;
    __syncthreads();

    // serial prefix-combine over the 16 chunks (associative compositing)
    if (threadIdx.x < PIX) {
        const int p = threadIdx.x;
        float Tg = 1.f, r = 0.f, g = 0.f, b = 0.f;
        #pragma unroll
        for (int c = 0; c < CH; ++c) {
            r += Tg * s_r[c][p];
            g += Tg * s_g[c][p];
            b += Tg * s_b[c][p];
            Tg *= s_T[c][p];
        }
        const int pix2 = pbase + p;
        const int py2 = pix2 / WW, px2 = pix2 % WW;
        out[((iv*3 + 0)*HH + py2)*WW + px2] = r;
        out[((iv*3 + 1)*HH + py2)*WW + px2] = g;
        out[((iv*3 + 2)*HH + py2)*WW + px2] = b;
    }
}

extern "C" void kernel_launch(void* const* d_in, const int* in_sizes, int n_in,
                              void* d_out, int out_size, void* d_ws, size_t ws_size,
                              hipStream_t stream) {
    const float* xyz      = (const float*)d_in[0];
    const float* feats    = (const float*)d_in[1];
    const float* scaling  = (const float*)d_in[2];
    const float* rotation = (const float*)d_in[3];
    const float* opacity  = (const float*)d_in[4];
    // d_in[5] = height, d_in[6] = width (fixed 128x128)
    const float* C2W      = (const float*)d_in[7];
    const float* intr     = (const float*)d_in[8];

    float* ws  = (float*)d_ws;    // needs NV*NG*12*4 = 96 KiB
    float* out = (float*)d_out;

    prep_rank_kernel<<<NV*8, 256, 0, stream>>>(
        xyz, feats, scaling, rotation, opacity, C2W, intr, ws);

    render_kernel<<<NV * (HH*WW / PIX), 256, 0, stream>>>(ws, out);
}

// Round 6
// 89.474 us; speedup vs baseline: 1.3844x; 1.2583x over previous
//
#include <hip/hip_runtime.h>
#include <math.h>

#define NG 1024      // gaussians per view
#define HH 128
#define WW 128
#define NV 2         // views
#define SH_C0 0.28209479177387814f
#define SH_C1 0.4886025119029199f

#define RECF 12                     // floats per gaussian record (3x float4)
#define REC_SORT 0                  // sorted records (float offset in ws)

#define TILE 16                     // 16x16 pixel tiles
#define TPX  (WW/TILE)              // 8 tiles across
#define TPY  (HH/TILE)              // 8 tiles down
#define NT   (TPX*TPY)              // 64 tiles per view
#define RCH  128                    // records staged per LDS chunk

// ---------------- Kernel A: fused preprocess + rank + sorted scatter ----------------
// grid = NV*8 blocks x 256 threads.
// record: [u,v,A,B | C,pwmin,op,r | g,b,du_max,dv_max]  (A=-0.5ca, B=-cb, C=-0.5cc)
// du_max/dv_max: exact half-widths of the alpha>=1/255 support bbox (-1 if empty).
__global__ __launch_bounds__(256) void prep_rank_kernel(
    const float* __restrict__ xyz, const float* __restrict__ feats,
    const float* __restrict__ scaling, const float* __restrict__ rotation,
    const float* __restrict__ opacity, const float* __restrict__ C2W,
    const float* __restrict__ intr, float* __restrict__ ws)
{
    __shared__ unsigned long long s_key[NG];   // 8 KiB
    __shared__ int s_cnt[256];

    const int iv  = blockIdx.x >> 3;
    const int seg = blockIdx.x & 7;
    const int t   = threadIdx.x;

    const float* c2w = C2W + iv * 16;   // row-major 4x4
    // Rcw = R^T; row 2 of Rcw = column 2 of R
    const float r20 = c2w[2], r21 = c2w[6], r22 = c2w[10];
    const float tc2 = -(r20*c2w[3] + r21*c2w[7] + r22*c2w[11]);

    // ---- phase a: all 1024 depth keys of this view (4 per thread) ----
    #pragma unroll
    for (int k = 0; k < 4; ++k) {
        const int g = k*256 + t;
        const float X = xyz[g*3+0], Y = xyz[g*3+1], Z = xyz[g*3+2];
        const float pz = r20*X + r21*Y + r22*Z + tc2;
        // valid => pz > 0.2 > 0; invalid => 1e5. IEEE bits strictly monotone in z.
        const float zk = (pz > 0.2f) ? pz : 100000.0f;
        s_key[g] = (((unsigned long long)__float_as_uint(zk)) << 10)
                 | (unsigned long long)(unsigned)g;
    }
    __syncthreads();

    // ---- phase b: rank count (2 threads per gaussian, 512 keys each) ----
    const int g    = seg*128 + (t & 127);
    const int half = t >> 7;
    const unsigned long long ki = s_key[g];
    {
        const unsigned long long* kp = s_key + half*512;
        int cnt = 0;
        #pragma unroll 8
        for (int j = 0; j < 512; ++j)
            cnt += (kp[j] < ki) ? 1 : 0;
        s_cnt[t] = cnt;
    }
    __syncthreads();

    if (t >= 128) return;
    const int rank = s_cnt[t] + s_cnt[t+128];

    // ---- phase c: full preprocess for gaussian g, write to sorted slot ----
    const float fx = intr[iv*4+0], fy = intr[iv*4+1];
    const float cx = intr[iv*4+2], cy = intr[iv*4+3];

    float Rcw[3][3], tcw[3];
    #pragma unroll
    for (int r = 0; r < 3; ++r)
        #pragma unroll
        for (int c = 0; c < 3; ++c)
            Rcw[r][c] = c2w[c*4 + r];
    #pragma unroll
    for (int r = 0; r < 3; ++r)
        tcw[r] = -(Rcw[r][0]*c2w[3] + Rcw[r][1]*c2w[7] + Rcw[r][2]*c2w[11]);
    const float camx = c2w[3], camy = c2w[7], camz = c2w[11];

    const float X = xyz[g*3+0], Y = xyz[g*3+1], Z = xyz[g*3+2];

    // quaternion -> rotation
    float qw = rotation[g*4+0], qx = rotation[g*4+1];
    float qy = rotation[g*4+2], qz = rotation[g*4+3];
    const float qn = rsqrtf(qw*qw + qx*qx + qy*qy + qz*qz);
    qw *= qn; qx *= qn; qy *= qn; qz *= qn;
    const float R00 = 1.f - 2.f*(qy*qy + qz*qz);
    const float R01 = 2.f*(qx*qy - qw*qz);
    const float R02 = 2.f*(qx*qz + qw*qy);
    const float R10 = 2.f*(qx*qy + qw*qz);
    const float R11 = 1.f - 2.f*(qx*qx + qz*qz);
    const float R12 = 2.f*(qy*qz - qw*qx);
    const float R20 = 2.f*(qx*qz - qw*qy);
    const float R21 = 2.f*(qy*qz + qw*qx);
    const float R22 = 1.f - 2.f*(qx*qx + qy*qy);

    const float s0 = scaling[g*3+0], s1 = scaling[g*3+1], s2 = scaling[g*3+2];
    const float M00 = R00*s0, M01 = R01*s1, M02 = R02*s2;
    const float M10 = R10*s0, M11 = R11*s1, M12 = R12*s2;
    const float M20 = R20*s0, M21 = R21*s1, M22 = R22*s2;

    // cov3d = M M^T (symmetric)
    const float S00 = M00*M00 + M01*M01 + M02*M02;
    const float S01 = M00*M10 + M01*M11 + M02*M12;
    const float S02 = M00*M20 + M01*M21 + M02*M22;
    const float S11 = M10*M10 + M11*M11 + M12*M12;
    const float S12 = M10*M20 + M11*M21 + M12*M22;
    const float S22 = M20*M20 + M21*M21 + M22*M22;

    // cov_cam = Rcw * S * Rcw^T
    float tmp[3][3];
    const float S[3][3] = {{S00,S01,S02},{S01,S11,S12},{S02,S12,S22}};
    #pragma unroll
    for (int r = 0; r < 3; ++r)
        #pragma unroll
        for (int c = 0; c < 3; ++c)
            tmp[r][c] = Rcw[r][0]*S[0][c] + Rcw[r][1]*S[1][c] + Rcw[r][2]*S[2][c];
    float C[3][3];
    #pragma unroll
    for (int r = 0; r < 3; ++r)
        #pragma unroll
        for (int c = 0; c < 3; ++c)
            C[r][c] = tmp[r][0]*Rcw[c][0] + tmp[r][1]*Rcw[c][1] + tmp[r][2]*Rcw[c][2];

    // camera-space x,y; z recovered from the key so ordering & projection agree
    const float px_ = Rcw[0][0]*X + Rcw[0][1]*Y + Rcw[0][2]*Z + tcw[0];
    const float py_ = Rcw[1][0]*X + Rcw[1][1]*Y + Rcw[1][2]*Z + tcw[1];
    const float zf  = __uint_as_float((unsigned)(ki >> 10));
    const bool valid = zf < 99999.0f;            // invalid marker is 1e5

    const float zs = fmaxf(zf, 0.2f);
    const float izs = 1.f / zs;

    const float u = fx*px_*izs + cx;
    const float v = fy*py_*izs + cy;

    // J rows: (a00, 0, a02), (0, a11, a12)
    const float a00 = fx*izs;
    const float a02 = -fx*px_*izs*izs;
    const float a11 = fy*izs;
    const float a12 = -fy*py_*izs*izs;

    const float c00 = a00*a00*C[0][0] + 2.f*a00*a02*C[0][2] + a02*a02*C[2][2] + 0.3f;
    const float c01 = a00*a11*C[0][1] + a00*a12*C[0][2] + a02*a11*C[1][2] + a02*a12*C[2][2];
    const float c11 = a11*a11*C[1][1] + 2.f*a11*a12*C[1][2] + a12*a12*C[2][2] + 0.3f;

    const float det = fmaxf(c00*c11 - c01*c01, 1e-6f);
    const float idet = 1.f / det;

    // SH color (degree 1)
    float dx = X - camx, dy = Y - camy, dz = Z - camz;
    const float dn = rsqrtf(dx*dx + dy*dy + dz*dz);
    dx *= dn; dy *= dn; dz *= dn;
    const float* f = feats + g*12;   // [4][3]
    float col[3];
    #pragma unroll
    for (int c = 0; c < 3; ++c) {
        float cc_ = SH_C0*f[0*3+c] - SH_C1*dy*f[1*3+c] + SH_C1*dz*f[2*3+c]
                    - SH_C1*dx*f[3*3+c] + 0.5f;
        col[c] = fmaxf(cc_, 0.f);
    }

    const float op = valid ? opacity[g] : 0.f;
    const float pwmin = -logf(255.f * op);   // = -L; op=0 -> +inf -> always skipped

    // conic pre-negated/halved: pw = A*du^2 + C*dv^2 + B*du*dv
    const float Aq = -0.5f * (c11*idet);
    const float Bq = c01*idet;
    const float Cq = -0.5f * (c00*idet);

    // Exact support bbox of {alpha >= 1/255}: ellipse x^T Q x = 2L with
    // Q = conic; Q^{-1}_00 = c00, Q^{-1}_11 = c11 (det never clamps: diag +0.3
    // => det_raw > 0.09). du_max = sqrt(2L*c00). Empty if op < 1/255.
    float dumax = -1.f, dvmax = -1.f;
    if (op >= (1.f/255.f)) {
        const float L = -pwmin;              // log(255*op) >= 0
        dumax = sqrtf(2.f*L*c00);
        dvmax = sqrtf(2.f*L*c11);
    }

    float4* dst = (float4*)(ws + REC_SORT + (size_t)(iv*NG + rank)*RECF);
    dst[0] = make_float4(u,  v,  Aq,    Bq);
    dst[1] = make_float4(Cq, pwmin, op, col[0]);
    dst[2] = make_float4(col[1], col[2], dumax, dvmax);
}

// ---------------- Kernel B: tile-culled front-to-back compositing ----------------
// grid = NV*NT blocks (one per 16x16 tile), 256 threads (one per pixel).
// Phase 1: bbox-cull all 1024 sorted records against the tile (4 per thread).
// Phase 2: order-preserving compaction of survivor indices (block scan).
// Phase 3: each thread composites its pixel serially over the list (LDS-staged).
__global__ __launch_bounds__(256) void render_kernel(
    const float* __restrict__ ws, float* __restrict__ out)
{
    __shared__ unsigned short s_ids[NG];
    __shared__ int s_scan[256];
    __shared__ float4 s_rec[RCH*3];

    const int iv   = blockIdx.x / NT;
    const int tile = blockIdx.x % NT;
    const int tx0  = (tile % TPX) * TILE;
    const int ty0  = (tile / TPX) * TILE;
    const int t    = threadIdx.x;

    const float xlo = tx0 + 0.5f, xhi = tx0 + TILE - 0.5f;
    const float ylo = ty0 + 0.5f, yhi = ty0 + TILE - 0.5f;

    const float4* recs = (const float4*)(ws + REC_SORT + (size_t)iv*NG*3*4/4*0)
                       + (size_t)iv*NG*3;

    // ---- phase 1: test 4 contiguous sorted records per thread ----
    int flags = 0, cnt = 0;
    #pragma unroll
    for (int k = 0; k < 4; ++k) {
        const int gidx = t*4 + k;
        const float4 g0 = recs[gidx*3+0];   // u,v,A,B
        const float4 g2 = recs[gidx*3+2];   // g,b,du_max,dv_max
        const bool hit = (g0.x - g2.z <= xhi) && (g0.x + g2.z >= xlo)
                      && (g0.y - g2.w <= yhi) && (g0.y + g2.w >= ylo)
                      && (g2.z >= 0.f);
        flags |= (hit ? 1 : 0) << k;
        cnt   += hit ? 1 : 0;
    }
    s_scan[t] = cnt;
    __syncthreads();

    // ---- phase 2: inclusive Hillis-Steele scan over 256 counts ----
    #pragma unroll
    for (int d = 1; d < 256; d <<= 1) {
        const int vv = (t >= d) ? s_scan[t-d] : 0;
        __syncthreads();
        s_scan[t] += vv;
        __syncthreads();
    }
    int base = s_scan[t] - cnt;              // exclusive prefix
    const int m = s_scan[255];               // total survivors
    #pragma unroll
    for (int k = 0; k < 4; ++k) {
        if (flags & (1 << k)) s_ids[base++] = (unsigned short)(t*4 + k);
    }
    __syncthreads();

    // ---- phase 3: per-pixel sequential compositing over the culled list ----
    const int px = tx0 + (t & (TILE-1));
    const int py = ty0 + (t >> 4);
    const float gx = px + 0.5f;
    const float gy = py + 0.5f;

    float T = 1.f, ar = 0.f, ag = 0.f, ab = 0.f;

    for (int c0 = 0; c0 < m; c0 += RCH) {
        const int nc = min(RCH, m - c0);
        // stage nc records into LDS (cooperative, 16B lanes)
        for (int idx = t; idx < nc*3; idx += 256) {
            const int rid = s_ids[c0 + idx/3];
            s_rec[idx] = recs[rid*3 + idx%3];
        }
        __syncthreads();

        if (T >= 1e-5f) {
            for (int j = 0; j < nc; ++j) {
                const float4 g0 = s_rec[j*3+0];   // u,v,A,B
                const float4 g1 = s_rec[j*3+1];   // C,pwmin,op,r
                const float du = gx - g0.x;
                const float dv = gy - g0.y;
                const float pw = fmaf(g0.z, du*du, fmaf(g1.x, dv*dv, g0.w*(du*dv)));
                if (pw <= 0.f && pw >= g1.y) {
                    const float al = fminf(0.99f, g1.z * __expf(pw));
                    if (al >= (1.f/255.f)) {
                        const float4 g2 = s_rec[j*3+2];  // g,b,-,-
                        const float w = al * T;
                        ar += w * g1.w;
                        ag += w * g2.x;
                        ab += w * g2.y;
                        T *= (1.f - al);
                        if (T < 1e-5f) break;
                    }
                }
            }
        }
        __syncthreads();
    }

    out[((iv*3 + 0)*HH + py)*WW + px] = ar;
    out[((iv*3 + 1)*HH + py)*WW + px] = ag;
    out[((iv*3 + 2)*HH + py)*WW + px] = ab;
}

extern "C" void kernel_launch(void* const* d_in, const int* in_sizes, int n_in,
                              void* d_out, int out_size, void* d_ws, size_t ws_size,
                              hipStream_t stream) {
    const float* xyz      = (const float*)d_in[0];
    const float* feats    = (const float*)d_in[1];
    const float* scaling  = (const float*)d_in[2];
    const float* rotation = (const float*)d_in[3];
    const float* opacity  = (const float*)d_in[4];
    // d_in[5] = height, d_in[6] = width (fixed 128x128)
    const float* C2W      = (const float*)d_in[7];
    const float* intr     = (const float*)d_in[8];

    float* ws  = (float*)d_ws;    // needs NV*NG*12*4 = 96 KiB
    float* out = (float*)d_out;

    prep_rank_kernel<<<NV*8, 256, 0, stream>>>(
        xyz, feats, scaling, rotation, opacity, C2W, intr, ws);

    render_kernel<<<NV*NT, 256, 0, stream>>>(ws, out);
}

// Round 7
// 88.602 us; speedup vs baseline: 1.3980x; 1.0098x over previous
//
#include <hip/hip_runtime.h>
#include <math.h>

#define NG 1024      // gaussians per view
#define HH 128
#define WW 128
#define NV 2         // views
#define SH_C0 0.28209479177387814f
#define SH_C1 0.4886025119029199f

#define RECF 12                     // floats per gaussian record (3x float4)

#define TILE 16                     // 16x16 pixel tiles
#define TPX  (WW/TILE)              // 8 tiles across
#define TPY  (HH/TILE)              // 8 tiles down
#define NT   (TPX*TPY)              // 64 tiles per view
#define RCH  256                    // records staged per LDS chunk

// record layout (3x float4 per gaussian, depth-sorted):
//   rec0 = (u, v, dumax, dvmax)   -- position + exact alpha>=1/255 support bbox
//   rec1 = (A, B, C, pwmin)       -- conic, pre-negated/halved: pw = A du^2 + C dv^2 + B du dv
//   rec2 = (op, r, g, b)
// dumax = -1 marks an empty-support (skipped) gaussian.

// ---------------- Kernel A: fused preprocess + rank + sorted scatter ----------------
__global__ __launch_bounds__(256) void prep_rank_kernel(
    const float* __restrict__ xyz, const float* __restrict__ feats,
    const float* __restrict__ scaling, const float* __restrict__ rotation,
    const float* __restrict__ opacity, const float* __restrict__ C2W,
    const float* __restrict__ intr, float* __restrict__ ws)
{
    __shared__ unsigned long long s_key[NG];   // 8 KiB
    __shared__ int s_cnt[256];

    const int iv  = blockIdx.x >> 3;
    const int seg = blockIdx.x & 7;
    const int t   = threadIdx.x;

    const float* c2w = C2W + iv * 16;   // row-major 4x4
    // Rcw = R^T; row 2 of Rcw = column 2 of R
    const float r20 = c2w[2], r21 = c2w[6], r22 = c2w[10];
    const float tc2 = -(r20*c2w[3] + r21*c2w[7] + r22*c2w[11]);

    // ---- phase a: all 1024 depth keys of this view (4 per thread) ----
    #pragma unroll
    for (int k = 0; k < 4; ++k) {
        const int g = k*256 + t;
        const float X = xyz[g*3+0], Y = xyz[g*3+1], Z = xyz[g*3+2];
        const float pz = r20*X + r21*Y + r22*Z + tc2;
        // valid => pz > 0.2 > 0; invalid => 1e5. IEEE bits strictly monotone in z.
        const float zk = (pz > 0.2f) ? pz : 100000.0f;
        s_key[g] = (((unsigned long long)__float_as_uint(zk)) << 10)
                 | (unsigned long long)(unsigned)g;
    }
    __syncthreads();

    // ---- phase b: rank count (2 threads per gaussian, 512 keys each) ----
    const int g    = seg*128 + (t & 127);
    const int half = t >> 7;
    const unsigned long long ki = s_key[g];
    {
        const unsigned long long* kp = s_key + half*512;
        int cnt = 0;
        #pragma unroll 8
        for (int j = 0; j < 512; ++j)
            cnt += (kp[j] < ki) ? 1 : 0;
        s_cnt[t] = cnt;
    }
    __syncthreads();

    if (t >= 128) return;
    const int rank = s_cnt[t] + s_cnt[t+128];

    // ---- phase c: full preprocess for gaussian g, write to sorted slot ----
    const float fx = intr[iv*4+0], fy = intr[iv*4+1];
    const float cx = intr[iv*4+2], cy = intr[iv*4+3];

    float Rcw[3][3], tcw[3];
    #pragma unroll
    for (int r = 0; r < 3; ++r)
        #pragma unroll
        for (int c = 0; c < 3; ++c)
            Rcw[r][c] = c2w[c*4 + r];
    #pragma unroll
    for (int r = 0; r < 3; ++r)
        tcw[r] = -(Rcw[r][0]*c2w[3] + Rcw[r][1]*c2w[7] + Rcw[r][2]*c2w[11]);
    const float camx = c2w[3], camy = c2w[7], camz = c2w[11];

    const float X = xyz[g*3+0], Y = xyz[g*3+1], Z = xyz[g*3+2];

    // quaternion -> rotation
    float qw = rotation[g*4+0], qx = rotation[g*4+1];
    float qy = rotation[g*4+2], qz = rotation[g*4+3];
    const float qn = rsqrtf(qw*qw + qx*qx + qy*qy + qz*qz);
    qw *= qn; qx *= qn; qy *= qn; qz *= qn;
    const float R00 = 1.f - 2.f*(qy*qy + qz*qz);
    const float R01 = 2.f*(qx*qy - qw*qz);
    const float R02 = 2.f*(qx*qz + qw*qy);
    const float R10 = 2.f*(qx*qy + qw*qz);
    const float R11 = 1.f - 2.f*(qx*qx + qz*qz);
    const float R12 = 2.f*(qy*qz - qw*qx);
    const float R20 = 2.f*(qx*qz - qw*qy);
    const float R21 = 2.f*(qy*qz + qw*qx);
    const float R22 = 1.f - 2.f*(qx*qx + qy*qy);

    const float s0 = scaling[g*3+0], s1 = scaling[g*3+1], s2 = scaling[g*3+2];
    const float M00 = R00*s0, M01 = R01*s1, M02 = R02*s2;
    const float M10 = R10*s0, M11 = R11*s1, M12 = R12*s2;
    const float M20 = R20*s0, M21 = R21*s1, M22 = R22*s2;

    // cov3d = M M^T (symmetric)
    const float S00 = M00*M00 + M01*M01 + M02*M02;
    const float S01 = M00*M10 + M01*M11 + M02*M12;
    const float S02 = M00*M20 + M01*M21 + M02*M22;
    const float S11 = M10*M10 + M11*M11 + M12*M12;
    const float S12 = M10*M20 + M11*M21 + M12*M22;
    const float S22 = M20*M20 + M21*M21 + M22*M22;

    // cov_cam = Rcw * S * Rcw^T
    float tmp[3][3];
    const float S[3][3] = {{S00,S01,S02},{S01,S11,S12},{S02,S12,S22}};
    #pragma unroll
    for (int r = 0; r < 3; ++r)
        #pragma unroll
        for (int c = 0; c < 3; ++c)
            tmp[r][c] = Rcw[r][0]*S[0][c] + Rcw[r][1]*S[1][c] + Rcw[r][2]*S[2][c];
    float C[3][3];
    #pragma unroll
    for (int r = 0; r < 3; ++r)
        #pragma unroll
        for (int c = 0; c < 3; ++c)
            C[r][c] = tmp[r][0]*Rcw[c][0] + tmp[r][1]*Rcw[c][1] + tmp[r][2]*Rcw[c][2];

    // camera-space x,y; z recovered from the key so ordering & projection agree
    const float px_ = Rcw[0][0]*X + Rcw[0][1]*Y + Rcw[0][2]*Z + tcw[0];
    const float py_ = Rcw[1][0]*X + Rcw[1][1]*Y + Rcw[1][2]*Z + tcw[1];
    const float zf  = __uint_as_float((unsigned)(ki >> 10));
    const bool valid = zf < 99999.0f;            // invalid marker is 1e5

    const float zs = fmaxf(zf, 0.2f);
    const float izs = 1.f / zs;

    const float u = fx*px_*izs + cx;
    const float v = fy*py_*izs + cy;

    // J rows: (a00, 0, a02), (0, a11, a12)
    const float a00 = fx*izs;
    const float a02 = -fx*px_*izs*izs;
    const float a11 = fy*izs;
    const float a12 = -fy*py_*izs*izs;

    const float c00 = a00*a00*C[0][0] + 2.f*a00*a02*C[0][2] + a02*a02*C[2][2] + 0.3f;
    const float c01 = a00*a11*C[0][1] + a00*a12*C[0][2] + a02*a11*C[1][2] + a02*a12*C[2][2];
    const float c11 = a11*a11*C[1][1] + 2.f*a11*a12*C[1][2] + a12*a12*C[2][2] + 0.3f;

    const float det = fmaxf(c00*c11 - c01*c01, 1e-6f);
    const float idet = 1.f / det;

    // SH color (degree 1)
    float dx = X - camx, dy = Y - camy, dz = Z - camz;
    const float dn = rsqrtf(dx*dx + dy*dy + dz*dz);
    dx *= dn; dy *= dn; dz *= dn;
    const float* f = feats + g*12;   // [4][3]
    float col[3];
    #pragma unroll
    for (int c = 0; c < 3; ++c) {
        float cc_ = SH_C0*f[0*3+c] - SH_C1*dy*f[1*3+c] + SH_C1*dz*f[2*3+c]
                    - SH_C1*dx*f[3*3+c] + 0.5f;
        col[c] = fmaxf(cc_, 0.f);
    }

    const float op = valid ? opacity[g] : 0.f;
    const float pwmin = -logf(255.f * op);   // = -L; op=0 -> +inf -> always skipped

    // conic pre-negated/halved
    const float Aq = -0.5f * (c11*idet);
    const float Bq = c01*idet;
    const float Cq = -0.5f * (c00*idet);

    // Exact support bbox of {alpha >= 1/255}: du_max = sqrt(2L*c00),
    // dv_max = sqrt(2L*c11) (det never clamps: diag +0.3 => det_raw > 0.09).
    float dumax = -1.f, dvmax = -1.f;
    if (op >= (1.f/255.f)) {
        const float L = -pwmin;              // log(255*op) >= 0
        dumax = sqrtf(2.f*L*c00);
        dvmax = sqrtf(2.f*L*c11);
    }

    float4* dst = (float4*)(ws + (size_t)(iv*NG + rank)*RECF);
    dst[0] = make_float4(u,  v,  dumax, dvmax);
    dst[1] = make_float4(Aq, Bq, Cq,    pwmin);
    dst[2] = make_float4(op, col[0], col[1], col[2]);
}

// ---------------- Kernel B: tile-culled front-to-back compositing ----------------
// grid = NV*NT blocks (one per 16x16 tile), 256 threads (one per pixel).
__global__ __launch_bounds__(256) void render_kernel(
    const float* __restrict__ ws, float* __restrict__ out)
{
    __shared__ unsigned short s_ids[NG];
    __shared__ int s_wsum[4];
    __shared__ float4 s_rec[RCH*3];

    const int iv   = blockIdx.x / NT;
    const int tile = blockIdx.x % NT;
    const int tx0  = (tile % TPX) * TILE;
    const int ty0  = (tile / TPX) * TILE;
    const int t    = threadIdx.x;
    const int lane = t & 63;
    const int wid  = t >> 6;

    const float xlo = tx0 + 0.5f, xhi = tx0 + TILE - 0.5f;
    const float ylo = ty0 + 0.5f, yhi = ty0 + TILE - 0.5f;

    const float4* recs = (const float4*)ws + (size_t)iv*NG*3;

    // ---- phase 1: bbox-cull 4 contiguous sorted records per thread (1 load each) ----
    int flags = 0, cnt = 0;
    #pragma unroll
    for (int k = 0; k < 4; ++k) {
        const int gidx = t*4 + k;
        const float4 g0 = recs[gidx*3+0];   // u,v,dumax,dvmax
        const bool hit = (g0.z >= 0.f)
                      && (g0.x - g0.z <= xhi) && (g0.x + g0.z >= xlo)
                      && (g0.y - g0.w <= yhi) && (g0.y + g0.w >= ylo);
        flags |= (hit ? 1 : 0) << k;
        cnt   += hit ? 1 : 0;
    }

    // ---- phase 2: order-preserving compaction via wave-shuffle prefix scan ----
    int v = cnt;
    #pragma unroll
    for (int d = 1; d < 64; d <<= 1) {
        const int n = __shfl_up(v, d, 64);
        if (lane >= d) v += n;
    }
    if (lane == 63) s_wsum[wid] = v;        // wave totals
    __syncthreads();
    int waveOff = 0;
    #pragma unroll
    for (int w = 0; w < 4; ++w)
        if (w < wid) waveOff += s_wsum[w];
    const int m = s_wsum[0] + s_wsum[1] + s_wsum[2] + s_wsum[3];
    int base = waveOff + v - cnt;           // exclusive prefix, global gidx order
    #pragma unroll
    for (int k = 0; k < 4; ++k) {
        if (flags & (1 << k)) s_ids[base++] = (unsigned short)(t*4 + k);
    }
    __syncthreads();

    // ---- phase 3: per-pixel sequential compositing over the culled list ----
    const int px = tx0 + (t & (TILE-1));
    const int py = ty0 + (t >> 4);
    const float gx = px + 0.5f;
    const float gy = py + 0.5f;

    float T = 1.f, ar = 0.f, ag = 0.f, ab = 0.f;

    for (int c0 = 0; c0 < m; c0 += RCH) {
        const int nc = min(RCH, m - c0);
        // stage nc records into LDS (cooperative, 16B lanes)
        for (int idx = t; idx < nc*3; idx += 256) {
            const int rid = s_ids[c0 + idx/3];
            s_rec[idx] = recs[rid*3 + idx%3];
        }
        __syncthreads();

        if (T >= 1e-5f) {
            for (int j = 0; j < nc; ++j) {
                const float4 g0 = s_rec[j*3+0];   // u,v,-,-
                const float4 g1 = s_rec[j*3+1];   // A,B,C,pwmin
                const float du = gx - g0.x;
                const float dv = gy - g0.y;
                const float pw = fmaf(g1.x, du*du, fmaf(g1.z, dv*dv, g1.y*(du*dv)));
                if (pw <= 0.f && pw >= g1.w) {
                    const float4 g2 = s_rec[j*3+2];  // op,r,g,b
                    const float al = fminf(0.99f, g2.x * __expf(pw));
                    if (al >= (1.f/255.f)) {
                        const float w = al * T;
                        ar += w * g2.y;
                        ag += w * g2.z;
                        ab += w * g2.w;
                        T *= (1.f - al);
                        if (T < 1e-5f) break;
                    }
                }
            }
        }
        __syncthreads();
    }

    out[((iv*3 + 0)*HH + py)*WW + px] = ar;
    out[((iv*3 + 1)*HH + py)*WW + px] = ag;
    out[((iv*3 + 2)*HH + py)*WW + px] = ab;
}

extern "C" void kernel_launch(void* const* d_in, const int* in_sizes, int n_in,
                              void* d_out, int out_size, void* d_ws, size_t ws_size,
                              hipStream_t stream) {
    const float* xyz      = (const float*)d_in[0];
    const float* feats    = (const float*)d_in[1];
    const float* scaling  = (const float*)d_in[2];
    const float* rotation = (const float*)d_in[3];
    const float* opacity  = (const float*)d_in[4];
    // d_in[5] = height, d_in[6] = width (fixed 128x128)
    const float* C2W      = (const float*)d_in[7];
    const float* intr     = (const float*)d_in[8];

    float* ws  = (float*)d_ws;    // needs NV*NG*12*4 = 96 KiB
    float* out = (float*)d_out;

    prep_rank_kernel<<<NV*8, 256, 0, stream>>>(
        xyz, feats, scaling, rotation, opacity, C2W, intr, ws);

    render_kernel<<<NV*NT, 256, 0, stream>>>(ws, out);
}